// Round 1
// 267.195 us; speedup vs baseline: 1.0456x; 1.0456x over previous
//
#include <hip/hip_runtime.h>

// Problem constants (fixed by setup_inputs)
#define B_   8
#define NN   2000
#define EE   20
#define HH   128
#define BN   (B_*NN)      // 16000 rows of x
#define NE   (NN*EE)      // 40000 e-rows per batch

typedef unsigned short ushort_t;
typedef __bf16 bf16x8 __attribute__((ext_vector_type(8)));
typedef float  f32x4  __attribute__((ext_vector_type(4)));
typedef float  f4     __attribute__((ext_vector_type(4)));
typedef unsigned short us8 __attribute__((ext_vector_type(8)));
typedef unsigned short us4 __attribute__((ext_vector_type(4)));

union FragU { us8 u; bf16x8 b; };
union Frag32 { unsigned int w[4]; us8 u; bf16x8 b; };

__device__ __forceinline__ float b2f(ushort_t v) {
    union { unsigned int i; float f; } c; c.i = ((unsigned int)v) << 16; return c.f;
}
__device__ __forceinline__ ushort_t f2b(float f) {   // RNE fp32 -> bf16
    union { float f; unsigned int i; } c; c.f = f;
    unsigned int r = (c.i + 0x7FFFu + ((c.i >> 16) & 1u)) >> 16;
    return (ushort_t)r;
}

// ---------------------------------------------------------------------------
// K1: Uxb = bf16(x@Wu + bu), Vxb = bf16(x@Wv + bv)   (both -> ws)
// (unchanged from previous round — ~4-8us, not the bottleneck)
// ---------------------------------------------------------------------------
__global__ __launch_bounds__(256) void k1_embed(
    const float* __restrict__ x,
    const float* __restrict__ Wu, const float* __restrict__ bu,
    const float* __restrict__ Wv, const float* __restrict__ bv,
    ushort_t* __restrict__ Uxb, ushort_t* __restrict__ Vxb)
{
    const int tid  = threadIdx.x;
    const int lane = tid & 63;
    const int wave = tid >> 6;
    const int wm = wave >> 1, wn = wave & 1;
    const int q  = lane >> 4, ln = lane & 15;
    const int m0 = blockIdx.x * 64;
    const int sel = blockIdx.y;
    const float* W    = sel ? Wv : Wu;
    const float* bias = sel ? bv : bu;
    ushort_t* dst = sel ? Vxb : Uxb;

    FragU af[2][4];  // [tm][ki]
#pragma unroll
    for (int tm = 0; tm < 2; ++tm)
#pragma unroll
        for (int ki = 0; ki < 4; ++ki) {
            const float* p = x + (size_t)(m0 + wm * 32 + tm * 16 + ln) * HH + ki * 32 + q * 8;
            f4 lo = *(const f4*)(p);
            f4 hi = *(const f4*)(p + 4);
            us8 t;
#pragma unroll
            for (int r = 0; r < 4; ++r) { t[r] = f2b(lo[r]); t[r + 4] = f2b(hi[r]); }
            af[tm][ki].u = t;
        }

    FragU bf[4][4];  // [ki][tn]
#pragma unroll
    for (int ki = 0; ki < 4; ++ki)
#pragma unroll
        for (int tn = 0; tn < 4; ++tn) {
            int n = wn * 64 + tn * 16 + ln;
            us8 t;
#pragma unroll
            for (int i = 0; i < 8; ++i) t[i] = f2b(W[(ki * 32 + q * 8 + i) * HH + n]);
            bf[ki][tn].u = t;
        }

    f32x4 acc[2][4];
#pragma unroll
    for (int tm = 0; tm < 2; ++tm)
#pragma unroll
        for (int tn = 0; tn < 4; ++tn) acc[tm][tn] = (f32x4){0.f, 0.f, 0.f, 0.f};

#pragma unroll
    for (int ki = 0; ki < 4; ++ki)
#pragma unroll
        for (int tm = 0; tm < 2; ++tm)
#pragma unroll
            for (int tn = 0; tn < 4; ++tn)
                acc[tm][tn] = __builtin_amdgcn_mfma_f32_16x16x32_bf16(
                    af[tm][ki].b, bf[ki][tn].b, acc[tm][tn], 0, 0, 0);

#pragma unroll
    for (int tn = 0; tn < 4; ++tn) {
        int col = wn * 64 + tn * 16 + ln;
        float bb = bias[col];
#pragma unroll
        for (int tm = 0; tm < 2; ++tm) {
            int rowb = m0 + wm * 32 + tm * 16 + q * 4;
#pragma unroll
            for (int r = 0; r < 4; ++r)
                dst[(size_t)(rowb + r) * HH + col] = f2b(acc[tm][tn][r] + bb);
        }
    }
}

// ---------------------------------------------------------------------------
// K2 v2: async-staged fused kernel.
//   - A tile (80 e-rows x 128 fp32, 40KB) staged via global_load_lds dwordx4:
//     40 wave-insts posted at block entry, zero VGPR, zero staging VALU.
//     HBM demand for the whole tile is in flight while B-frags load (L2).
//   - LDS layout: linear rows of 512B; 16B slots XOR-swizzled by (row&7):
//     source address carries the inverse swizzle (rule 21: both-sides-or-
//     neither), ds_read_b128 applies the same XOR -> uniform 8 dw/bank
//     (minimum aliasing for b128 = conflict-free).
//   - fp32->bf16 conversion at fragment read via v_cvt_pk_bf16_f32 (4/frag),
//     overlapped with MFMA by the scheduler.
//   - CT (128 x CSTR us = 21504B) and sidx alias into the dead A buffer
//     after the post-GEMM barrier -> LDS = exactly 40960B -> 4 blocks/CU.
// ---------------------------------------------------------------------------
#define CSTR 84    // CT stride (ushorts): 42 dwords (gcd 2 w/32) -> ~4-way max

__global__ __launch_bounds__(256, 4) void k2_fused(
    const float* __restrict__ e, const float* __restrict__ We,
    const int* __restrict__ eidx,
    const ushort_t* __restrict__ Uxb, const ushort_t* __restrict__ Vxb,
    float* __restrict__ out)
{
    // One 40KB buffer: phase 1 = A tile (80 rows x 512B, swizzled fp32),
    // phase 2 = CT (21504B at offset 0) + sidx (320B at byte 38400).
    __shared__ __align__(16) unsigned char smem[40960];

    const int tid  = threadIdx.x;
    const int lane = tid & 63;
    const int wave = tid >> 6;            // owns cols [wave*32, wave*32+32)
    const int q  = lane >> 4, ln = lane & 15;

    const int b   = blockIdx.y;
    const int nl0 = blockIdx.x * 4;       // first node (local)
    const size_t erow0 = (size_t)b * NE + (size_t)nl0 * EE;  // 80 rows

    // ---- async stage: 80 rows x 512B = 40 wave-insts, 10 per wave ----------
    // wave-inst i covers row pair r0 = wave*20 + 2*i (1KB linear LDS).
    // lane -> LDS byte r0*512 + lane*16  == row r0+(lane>>5), slot lane&31.
    // source slot = (lane&31) ^ (row&7)  (inverse of the read-side swizzle).
    {
        const int rl = lane >> 5;          // 0/1: which row of the pair
        const int sl = lane & 31;          // 16B slot within row
#pragma unroll
        for (int i = 0; i < 10; ++i) {
            const int r0 = wave * 20 + 2 * i;
            const int r  = r0 + rl;
            const int ss = sl ^ (r & 7);
            const float* gp = e + (erow0 + r) * (size_t)HH + (ss << 2);
            __builtin_amdgcn_global_load_lds(
                (const __attribute__((address_space(1))) void*)gp,
                (__attribute__((address_space(3))) void*)(smem + r0 * 512),
                16, 0, 0);
        }
    }

    // ---- B fragments (We, L2-hot) — overlaps the in-flight stage ----------
    FragU bfr[4][2];  // [ki][tn]
#pragma unroll
    for (int ki = 0; ki < 4; ++ki)
#pragma unroll
        for (int tn = 0; tn < 2; ++tn) {
            int n = wave * 32 + tn * 16 + ln;
            us8 t;
#pragma unroll
            for (int i = 0; i < 8; ++i) t[i] = f2b(We[(ki * 32 + q * 8 + i) * HH + n]);
            bfr[ki][tn].u = t;
        }

    f32x4 acc[5][2];
#pragma unroll
    for (int tm = 0; tm < 5; ++tm)
#pragma unroll
        for (int tn = 0; tn < 2; ++tn) acc[tm][tn] = (f32x4){0.f, 0.f, 0.f, 0.f};

    asm volatile("s_waitcnt vmcnt(0)" ::: "memory");
    __syncthreads();

    // ---- GEMM: swizzled fp32 fragment reads + cvt_pk -> bf16 -> MFMA ------
    const float* As = (const float*)smem;
#pragma unroll
    for (int ki = 0; ki < 4; ++ki) {
        Frag32 af[5];
#pragma unroll
        for (int tm = 0; tm < 5; ++tm) {
            const int r  = tm * 16 + ln;
            const int sw = r & 7;
            const int s0 = ki * 8 + q * 2;
            f4 lo = *(const f4*)(As + r * 128 + ((s0    ) ^ sw) * 4);
            f4 hi = *(const f4*)(As + r * 128 + ((s0 + 1) ^ sw) * 4);
            asm("v_cvt_pk_bf16_f32 %0, %1, %2" : "=v"(af[tm].w[0]) : "v"(lo[0]), "v"(lo[1]));
            asm("v_cvt_pk_bf16_f32 %0, %1, %2" : "=v"(af[tm].w[1]) : "v"(lo[2]), "v"(lo[3]));
            asm("v_cvt_pk_bf16_f32 %0, %1, %2" : "=v"(af[tm].w[2]) : "v"(hi[0]), "v"(hi[1]));
            asm("v_cvt_pk_bf16_f32 %0, %1, %2" : "=v"(af[tm].w[3]) : "v"(hi[2]), "v"(hi[3]));
        }
#pragma unroll
        for (int tm = 0; tm < 5; ++tm)
#pragma unroll
            for (int tn = 0; tn < 2; ++tn)
                acc[tm][tn] = __builtin_amdgcn_mfma_f32_16x16x32_bf16(
                    af[tm].b, bfr[ki][tn].b, acc[tm][tn], 0, 0, 0);
    }

    __syncthreads();  // A reads done; smem becomes CT + sidx

    // sidx into dead A region (bytes 38400..38720, above CT's 21504)
    int* sidx = (int*)(smem + 38400);
    if (tid < 80) sidx[tid] = eidx[erow0 + tid];

    // CT[col][row] bf16: lane's 4 regs = 4 consecutive rows -> one us4 store
    ushort_t* CT = (ushort_t*)smem;
#pragma unroll
    for (int tm = 0; tm < 5; ++tm)
#pragma unroll
        for (int tn = 0; tn < 2; ++tn) {
            int col  = wave * 32 + tn * 16 + ln;
            int rowb = tm * 16 + q * 4;
            us4 pk;
#pragma unroll
            for (int r = 0; r < 4; ++r) pk[r] = f2b(acc[tm][tn][r]);
            *(us4*)(&CT[col * CSTR + rowb]) = pk;
        }

    __syncthreads();

    // ---- epilogue: 512 (g,h) items over 256 threads -> 2 each -------------
    const int h  = tid & 127;
    const int gp = tid >> 7;
#pragma unroll 1
    for (int j = 0; j < 2; ++j) {
        int g = gp + 2 * j;
        const ushort_t* ctp = &CT[h * CSTR + g * 20];
        float lv[20];
#pragma unroll
        for (int i = 0; i < 5; ++i) {
            us4 v = *(const us4*)(ctp + i * 4);
#pragma unroll
            for (int r = 0; r < 4; ++r) lv[i * 4 + r] = b2f(v[r]);
        }
        float mx = lv[0];
#pragma unroll
        for (int k = 1; k < EE; ++k) mx = fmaxf(mx, lv[k]);

        // gather neighbor Vxb (per k: 128 lanes x 2B contiguous)
        ushort_t gv[20];
        const int ib = g * 20;
#pragma unroll
        for (int k = 0; k < EE; ++k)
            gv[k] = Vxb[(size_t)(b * NN + sidx[ib + k]) * HH + h];

        float s = 0.f, a = 0.f;
#pragma unroll
        for (int k = 0; k < EE; ++k) {
            float p = __expf(lv[k] - mx);
            s += p;
            a = fmaf(p, b2f(gv[k]), a);
        }
        size_t orow = (size_t)(b * NN + nl0 + g) * HH + h;
        out[orow] = b2f(Uxb[orow]) + a / s;
    }
}

// ---------------------------------------------------------------------------
extern "C" void kernel_launch(void* const* d_in, const int* in_sizes, int n_in,
                              void* d_out, int out_size, void* d_ws, size_t ws_size,
                              hipStream_t stream) {
    const float* x  = (const float*)d_in[0];
    const float* e  = (const float*)d_in[1];
    const float* Wu = (const float*)d_in[2];
    const float* bu = (const float*)d_in[3];
    const float* Wv = (const float*)d_in[4];
    const float* bv = (const float*)d_in[5];
    const float* We = (const float*)d_in[6];
    // d_in[7] = be: cancels in softmax, unused
    const int*   eidx = (const int*)d_in[8];
    // d_in[9] = n_edges (=20), compiled in

    ushort_t* Uxb = (ushort_t*)d_ws;                                   // 4.096 MB
    ushort_t* Vxb = (ushort_t*)((char*)d_ws + (size_t)BN * HH * 2);    // 4.096 MB
    float*    o   = (float*)d_out;

    k1_embed<<<dim3(250, 2), 256, 0, stream>>>(x, Wu, bu, Wv, bv, Uxb, Vxb);
    k2_fused<<<dim3(500, 8), 256, 0, stream>>>(e, We, eidx, Uxb, Vxb, o);
}